// Round 3
// baseline (443.483 us; speedup 1.0000x reference)
//
#include <hip/hip_runtime.h>

typedef int int4v __attribute__((ext_vector_type(4)));
typedef int int16v __attribute__((ext_vector_type(16)));

#define BM 256
#define BN 256
#define BKB 128  // int8 bytes along K per K-tile = 4 MFMA K-steps of 32

// Async global->LDS, 16B per lane; HW writes wave-uniform base + lane*16.
__device__ __forceinline__ void async_copy16(const void* g, void* l) {
  __builtin_amdgcn_global_load_lds((const __attribute__((address_space(1))) void*)g,
                                   (__attribute__((address_space(3))) void*)l, 16, 0, 0);
}

// One dispatch: blocks [0,xb) reduce x (n4x float4s), rest reduce w.
__global__ __launch_bounds__(256) void absmax2_kernel(
    const float* __restrict__ x, size_t n4x,
    const float* __restrict__ w, size_t n4w,
    unsigned* __restrict__ out, int xb) {
  const float4* src;
  size_t n4;
  unsigned* dst;
  int bid, nb;
  if ((int)blockIdx.x < xb) {
    src = (const float4*)x; n4 = n4x; dst = out; bid = blockIdx.x; nb = xb;
  } else {
    src = (const float4*)w; n4 = n4w; dst = out + 1; bid = blockIdx.x - xb; nb = gridDim.x - xb;
  }
  size_t i = (size_t)bid * blockDim.x + threadIdx.x;
  size_t stride = (size_t)nb * blockDim.x;
  float m = 0.0f;
  for (; i < n4; i += stride) {
    float4 v = src[i];
    m = fmaxf(m, fmaxf(fmaxf(fabsf(v.x), fabsf(v.y)), fmaxf(fabsf(v.z), fabsf(v.w))));
  }
#pragma unroll
  for (int off = 32; off > 0; off >>= 1)
    m = fmaxf(m, __shfl_down(m, off, 64));
  __shared__ float red[4];
  int wave = threadIdx.x >> 6, lane = threadIdx.x & 63;
  if (lane == 0) red[wave] = m;
  __syncthreads();
  if (threadIdx.x == 0) {
    m = fmaxf(fmaxf(red[0], red[1]), fmaxf(red[2], red[3]));
    atomicMax(dst, __float_as_uint(m));  // non-negative: uint order == float order
  }
}

// One dispatch: quantize x -> qx (int8, [-128,127]) and w -> qw ([-127,127]).
__global__ __launch_bounds__(256) void quant2_kernel(
    const float* __restrict__ x, char* __restrict__ qx, size_t nx,
    const float* __restrict__ w, char* __restrict__ qw, size_t nw,
    const unsigned* __restrict__ amax, int xb) {
  const float* src;
  char* dst;
  size_t n;
  float r, lo;
  int bid, nb;
  if ((int)blockIdx.x < xb) {
    src = x; dst = qx; n = nx; r = 127.0f / __uint_as_float(amax[0]);
    lo = -128.0f; bid = blockIdx.x; nb = xb;
  } else {
    src = w; dst = qw; n = nw; r = 127.0f / __uint_as_float(amax[1]);
    lo = -127.0f; bid = blockIdx.x - xb; nb = gridDim.x - xb;
  }
  size_t i = ((size_t)bid * blockDim.x + threadIdx.x) * 8;
  size_t stride = (size_t)nb * blockDim.x * 8;
  for (; i < n; i += stride) {
    float4 v0 = *(const float4*)(src + i);
    float4 v1 = *(const float4*)(src + i + 4);
    float f[8] = {v0.x, v0.y, v0.z, v0.w, v1.x, v1.y, v1.z, v1.w};
    unsigned w0 = 0, w1 = 0;
#pragma unroll
    for (int j = 0; j < 4; ++j) {
      int q0 = (int)fminf(fmaxf(rintf(f[j] * r), lo), 127.0f);
      int q1 = (int)fminf(fmaxf(rintf(f[4 + j] * r), lo), 127.0f);
      w0 |= (unsigned)(q0 & 0xff) << (8 * j);
      w1 |= (unsigned)(q1 & 0xff) << (8 * j);
    }
    uint2 u; u.x = w0; u.y = w1;
    *(uint2*)(dst + i) = u;
  }
}

// ---------------------------------------------------------------------------
// 256x256 int8 GEMM, mfma_i32_32x32x32_i8, FINE-PHASE schedule (m196 lesson:
// coarse whole-tile scheduling loses the ds_read||MFMA interleave).
// Phase = one K-step of 32: {6 ds_read_b128; [stage]; barrier; setprio;
// 8 MFMA; setprio; [vmcnt]; barrier}. Per phase per CU: MFMA 585 cyc vs
// LDS ~256 cyc -> MFMA-bound with 2.3x headroom (round-1's 16x16 phases were
// LDS-bound: 384 > 292; round-2's coarse tile had no phase-locking).
// Staging: all 8 chunks of tile t+1 go to the OTHER buffer during phases 0-1
// of tile t (4 A-chunks, then 4 B-chunks), so the vmcnt(0) at phase 3 waits
// on loads >= 2 phases (~1200 cyc) old -> structurally free drain.
// Race-free: within a tile, writes target buf^1 only, reads target buf; the
// single closing barrier per phase keeps waves phase-locked; buffer handoff
// is protected by the tile-boundary barrier + vmcnt.
// ---------------------------------------------------------------------------

#define STAGE_A4(buf_, t_) do {                                                \
    const char* ga_ = gA + (size_t)(t_) * BKB;                                 \
    int r0_ = wave * 8;                                                        \
    async_copy16(ga_ + (size_t)(r0_      ) * K, &As[buf_][(r0_      ) * BKB]); \
    async_copy16(ga_ + (size_t)(r0_ +  64) * K, &As[buf_][(r0_ +  64) * BKB]); \
    async_copy16(ga_ + (size_t)(r0_ + 128) * K, &As[buf_][(r0_ + 128) * BKB]); \
    async_copy16(ga_ + (size_t)(r0_ + 192) * K, &As[buf_][(r0_ + 192) * BKB]); \
  } while (0)

#define STAGE_B4(buf_, t_) do {                                                \
    const char* gb_ = gB + (size_t)(t_) * BKB;                                 \
    int r0_ = wave * 8;                                                        \
    async_copy16(gb_ + (size_t)(r0_      ) * K, &Bs[buf_][(r0_      ) * BKB]); \
    async_copy16(gb_ + (size_t)(r0_ +  64) * K, &Bs[buf_][(r0_ +  64) * BKB]); \
    async_copy16(gb_ + (size_t)(r0_ + 128) * K, &Bs[buf_][(r0_ + 128) * BKB]); \
    async_copy16(gb_ + (size_t)(r0_ + 192) * K, &Bs[buf_][(r0_ + 192) * BKB]); \
  } while (0)

#define VM0 asm volatile("s_waitcnt vmcnt(0)" ::: "memory")
#define VMN ((void)0)
#define NOSTG ((void)0)

#define MFMA32 __builtin_amdgcn_mfma_i32_32x32x32_i8

// One phase: reads for this K-step, optional staging, barrier, 8 MFMA, barrier.
#define PHASE(bb_, so_, STG, VMW) do {                                         \
    asm volatile("" ::: "memory");                                             \
    const char* Ab_ = &As[bb_][(wr * 128 + r32) * BKB];                        \
    const char* Bb_ = &Bs[bb_][(wc * 64 + r32) * BKB];                         \
    int4v a0_ = *(const int4v*)(Ab_ + 0 * 32 * BKB + (so_));                   \
    int4v a1_ = *(const int4v*)(Ab_ + 1 * 32 * BKB + (so_));                   \
    int4v a2_ = *(const int4v*)(Ab_ + 2 * 32 * BKB + (so_));                   \
    int4v a3_ = *(const int4v*)(Ab_ + 3 * 32 * BKB + (so_));                   \
    int4v b0_ = *(const int4v*)(Bb_ + 0 * 32 * BKB + (so_));                   \
    int4v b1_ = *(const int4v*)(Bb_ + 1 * 32 * BKB + (so_));                   \
    STG;                                                                       \
    __builtin_amdgcn_s_barrier();                                              \
    __builtin_amdgcn_s_setprio(1);                                             \
    acc[0][0] = MFMA32(a0_, b0_, acc[0][0], 0, 0, 0);                          \
    acc[0][1] = MFMA32(a0_, b1_, acc[0][1], 0, 0, 0);                          \
    acc[1][0] = MFMA32(a1_, b0_, acc[1][0], 0, 0, 0);                          \
    acc[1][1] = MFMA32(a1_, b1_, acc[1][1], 0, 0, 0);                          \
    acc[2][0] = MFMA32(a2_, b0_, acc[2][0], 0, 0, 0);                          \
    acc[2][1] = MFMA32(a2_, b1_, acc[2][1], 0, 0, 0);                          \
    acc[3][0] = MFMA32(a3_, b0_, acc[3][0], 0, 0, 0);                          \
    acc[3][1] = MFMA32(a3_, b1_, acc[3][1], 0, 0, 0);                          \
    __builtin_amdgcn_s_setprio(0);                                             \
    VMW;                                                                       \
    asm volatile("" ::: "memory");                                             \
    __builtin_amdgcn_s_barrier();                                              \
  } while (0)

// One K-tile = 4 phases; staging of next tile in phases 0-1; vmcnt at phase 3.
#define TILE(bb_, STG0, STG1, VMW3) do {                                       \
    PHASE(bb_, so0, STG0, VMN);                                                \
    PHASE(bb_, so1, STG1, VMN);                                                \
    PHASE(bb_, so2, NOSTG, VMN);                                               \
    PHASE(bb_, so3, NOSTG, VMW3);                                              \
  } while (0)

__global__ __launch_bounds__(512, 2) void gemm_i8_kernel(
    const char* __restrict__ qx, const char* __restrict__ qw,
    const float* __restrict__ bias, const unsigned* __restrict__ amax,
    float* __restrict__ out, int M, int N, int K) {
  __shared__ __align__(16) char As[2][BM * BKB];  // 64 KB
  __shared__ __align__(16) char Bs[2][BN * BKB];  // 64 KB
  const int tid = threadIdx.x;
  const int wave = tid >> 6, lane = tid & 63;
  const int wr = wave >> 2, wc = wave & 3;  // 2 (M) x 4 (N) waves

  // T1: XCD-aware swizzle (grid 512 % 8 == 0): each XCD gets a contiguous
  // tile chunk, bm fastest -> B panel stays hot in that XCD's L2.
  int tilesM = M / BM, tilesN = N / BN;
  int T = tilesM * tilesN;
  int p = blockIdx.x;
  int tile;
  if ((T & 7) == 0) tile = (p & 7) * (T >> 3) + (p >> 3);
  else tile = p;
  int bm = (tile % tilesM) * BM;
  int bn = (tile / tilesM) * BN;

  // T2 staging (rule #21): LDS dest linear, global source pre-swizzled.
  // LDS (row, slot s) holds global (row, s ^ (row&7)); 16B slots, 8/row.
  const int grow = lane >> 3;                    // row within 8-row group
  const int gcol = ((lane & 7) ^ grow) * 16;     // pre-swizzled source col
  const char* gA = qx + (size_t)(bm + grow) * K + gcol;
  const char* gB = qw + (size_t)(bn + grow) * K + gcol;

  // Read side: fragment row = base + (lane&31), bases multiples of 32,
  // so row&7 == lane&7. K-chunk for kstep ks = ks*2 + (lane>>5).
  const int r32 = lane & 31, hi = lane >> 5, l7 = lane & 7;
  const int so0 = ((0 + hi) ^ l7) * 16;
  const int so1 = ((2 + hi) ^ l7) * 16;
  const int so2 = ((4 + hi) ^ l7) * 16;
  const int so3 = ((6 + hi) ^ l7) * 16;

  const int NT = K >> 7;  // K-tiles of 128 (K=4096 -> 32, even)

  int16v acc[4][2] = {};  // [m][n] 32x32 tiles; 128 acc regs

  // Prologue: tile 0 into buf 0.
  STAGE_A4(0, 0);
  STAGE_B4(0, 0);
  VM0;
  __builtin_amdgcn_s_barrier();

  int t = 0;
  for (; t < NT - 2; t += 2) {
    TILE(0, STAGE_A4(1, t + 1), STAGE_B4(1, t + 1), VM0);
    TILE(1, STAGE_A4(0, t + 2), STAGE_B4(0, t + 2), VM0);
  }
  // t == NT-2: stage last tile, then pure-compute final tile.
  TILE(0, STAGE_A4(1, NT - 1), STAGE_B4(1, NT - 1), VM0);
  TILE(1, NOSTG, NOSTG, VMN);

  // Epilogue. C/D layout for 32x32 (m74/m101, dtype-independent):
  // col = lane&31 (n-dim), row = (reg&3) + 8*(reg>>2) + 4*(lane>>5) (m-dim).
  float fx = __uint_as_float(amax[0]) * (1.0f / 127.0f);
  float fw = __uint_as_float(amax[1]) * (1.0f / 127.0f);
  float scale = 4.0f * fx * fw;
  int col = lane & 31;
  int rbh = 4 * hi;
#pragma unroll
  for (int n = 0; n < 2; ++n) {
    int gn = bn + wc * 64 + n * 32 + col;
    float b4 = 4.0f * bias[gn];
#pragma unroll
    for (int m = 0; m < 4; ++m) {
      size_t rowb = (size_t)(bm + wr * 128 + m * 32 + rbh);
#pragma unroll
      for (int g = 0; g < 4; ++g)
#pragma unroll
        for (int rr = 0; rr < 4; ++rr)
          __builtin_nontemporal_store(
              scale * (float)acc[m][n][g * 4 + rr] + b4,
              out + (rowb + g * 8 + rr) * N + gn);
    }
  }
}

extern "C" void kernel_launch(void* const* d_in, const int* in_sizes, int n_in,
                              void* d_out, int out_size, void* d_ws, size_t ws_size,
                              hipStream_t stream) {
  const float* x = (const float*)d_in[0];
  const float* W = (const float*)d_in[1];
  const float* b = (const float*)d_in[2];
  float* out = (float*)d_out;

  int Nv = in_sizes[2];          // OUT = 4096
  int K = in_sizes[1] / Nv;      // IN  = 4096
  int M = in_sizes[0] / K;       // N rows = 8192

  size_t nx = (size_t)M * K, nw = (size_t)Nv * K;
  unsigned* amax = (unsigned*)d_ws;        // [0]=max|x| bits, [1]=max|W| bits
  char* qx = (char*)d_ws + 256;            // M*K int8
  char* qw = qx + nx;                      // Nv*K int8

  hipMemsetAsync(d_ws, 0, 8, stream);
  absmax2_kernel<<<1536, 256, 0, stream>>>(x, nx / 4, W, nw / 4, amax, 1024);
  quant2_kernel<<<3072, 256, 0, stream>>>(x, qx, nx, W, qw, nw, amax, 2048);
  gemm_i8_kernel<<<(M / BM) * (Nv / BN), 512, 0, stream>>>(qx, qw, b, amax, out, M, Nv, K);
}